// Round 8
// baseline (179.002 us; speedup 1.0000x reference)
//
#include <hip/hip_runtime.h>
#include <hip/hip_bf16.h>
#include <hip/hip_cooperative_groups.h>

#define B_ 8
#define D_ 128
#define NH 8
#define L_ 1024
#define DK 16

typedef __attribute__((ext_vector_type(4))) short s4;
typedef __attribute__((ext_vector_type(4))) float f4;

static __device__ __forceinline__ unsigned short f2bf(float f) {
    __hip_bfloat16 h = __float2bfloat16(f);
    return *reinterpret_cast<unsigned short*>(&h);
}
static __device__ __forceinline__ unsigned pack2(float a, float b) {
    return (unsigned)f2bf(a) | ((unsigned)f2bf(b) << 16);
}
static __device__ __forceinline__ s4 pack4(float a, float b, float c, float d) {
    union { unsigned u[2]; s4 v; } un;
    un.u[0] = pack2(a, b);
    un.u[1] = pack2(c, d);
    return un.v;
}

// 16x16x16 bf16 MFMA: D = A*B + C.  A[m=lane&15][k=(lane>>4)*4+jj],
// B[k=(lane>>4)*4+jj][n=lane&15], C/D[row=(lane>>4)*4+reg][col=lane&15].
// (A/B/C mapping HW-verified in rounds 4-7 end-to-end.)
#if __has_builtin(__builtin_amdgcn_mfma_f32_16x16x16_bf16)
#define MFMA16(a, b, c) __builtin_amdgcn_mfma_f32_16x16x16_bf16(a, b, c, 0, 0, 0)
#elif __has_builtin(__builtin_amdgcn_mfma_f32_16x16x16bf16_1k)
#define MFMA16(a, b, c) __builtin_amdgcn_mfma_f32_16x16x16bf16_1k(a, b, c, 0, 0, 0)
#else
static __device__ __forceinline__ f4 mfma16_asm(s4 a, s4 b, f4 c) {
    f4 d;
    asm volatile("v_mfma_f32_16x16x16_bf16 %0, %1, %2, %3"
                 : "=&v"(d) : "v"(a), "v"(b), "v"(c));
    return d;
}
#define MFMA16(a, b, c) mfma16_asm(a, b, c)
#endif

// ---------------------------------------------------------------------------
// Single cooperative kernel: 256 blocks x 256 threads (1 block/CU).
// Phase A (proj): 6144 wave-tasks (which 0..2, bh 0..63, 32-wide l-tile 0..31)
//   strided over the grid's 1024 waves; writes Qt[bh][l][k], Kt[bh][j][k]*.25,
//   Vt[bh][v][i] bf16 (all MFMA-operand-ready).
// grid.sync()
// Phase B (attn+out): block idx -> (b = idx>>5, jblk = (idx&31)*32).
//   Each wave: 2 heads x 2 j-tiles of flash-style column-softmax attention
//   (S = Qt*Kt, P = exp(S) reused in C-layout==B-layout, O += Vt*P),
//   normalized head tile -> LDS; then out = Wo @ hls from LDS.
// ---------------------------------------------------------------------------
__global__ __launch_bounds__(256)
void fused_kernel(const float* __restrict__ x,
                  const float* __restrict__ Wq,
                  const float* __restrict__ Wk,
                  const float* __restrict__ Wv,
                  const float* __restrict__ Wo,
                  unsigned short* __restrict__ Qt,
                  unsigned short* __restrict__ Kt,
                  unsigned short* __restrict__ Vt,
                  float* __restrict__ out) {
    const int lane = threadIdx.x & 63;
    const int wv   = threadIdx.x >> 6;
    const int m = lane & 15, q = lane >> 4;

    // ======== Phase A: QKV projection ========
    const int w = blockIdx.x * 4 + wv;          // global wave id, 0..1023
    for (int t = w; t < 6144; t += 1024) {
        const int n0    = (t & 31) * 32;
        const int bh    = (t >> 5) & 63;
        const int which = t >> 11;
        const int b = bh >> 3, h = bh & 7;

        const float* W = (which == 0) ? Wq : (which == 1) ? Wk : Wv;
        const float* Wrow = W + ((size_t)((h * B_ + b) * DK + m)) * D_;
        const float* xb = x + (size_t)b * D_ * L_ + n0 + m;

        f4 acc0 = {0.f, 0.f, 0.f, 0.f}, acc1 = {0.f, 0.f, 0.f, 0.f};
#pragma unroll
        for (int kb = 0; kb < 8; ++kb) {
            const int k4 = kb * 16 + q * 4;
            float4 wf = *(const float4*)(Wrow + k4);
            s4 a = pack4(wf.x, wf.y, wf.z, wf.w);

            const float* xc = xb + (size_t)k4 * L_;
            float b00 = xc[0];           float b01 = xc[L_];
            float b02 = xc[2 * L_];      float b03 = xc[3 * L_];
            float b10 = xc[16];          float b11 = xc[L_ + 16];
            float b12 = xc[2 * L_ + 16]; float b13 = xc[3 * L_ + 16];
            s4 bf0 = pack4(b00, b01, b02, b03);
            s4 bf1 = pack4(b10, b11, b12, b13);

            acc0 = MFMA16(a, bf0, acc0);
            acc1 = MFMA16(a, bf1, acc1);
        }

        if (which == 2) {
            // D[row=v=q*4+r][col=i=n0(+16)+m] -> Vt[bh][v][i]
            unsigned short* vp = Vt + ((size_t)bh * DK + q * 4) * L_ + n0 + m;
            vp[0]      = f2bf(acc0[0]); vp[L_]     = f2bf(acc0[1]);
            vp[2 * L_] = f2bf(acc0[2]); vp[3 * L_] = f2bf(acc0[3]);
            vp += 16;
            vp[0]      = f2bf(acc1[0]); vp[L_]     = f2bf(acc1[1]);
            vp[2 * L_] = f2bf(acc1[2]); vp[3 * L_] = f2bf(acc1[3]);
        } else {
            const float sc = (which == 1) ? 0.25f : 1.0f;
            unsigned short* T = (which == 0) ? Qt : Kt;
            uint2 u0, u1;
            u0.x = pack2(acc0[0] * sc, acc0[1] * sc);
            u0.y = pack2(acc0[2] * sc, acc0[3] * sc);
            u1.x = pack2(acc1[0] * sc, acc1[1] * sc);
            u1.y = pack2(acc1[2] * sc, acc1[3] * sc);
            // D[row=k=q*4+r][col=l] -> T[bh][l][k]
            *(uint2*)(T + ((size_t)bh * L_ + n0 + m) * DK + q * 4)      = u0;
            *(uint2*)(T + ((size_t)bh * L_ + n0 + 16 + m) * DK + q * 4) = u1;
        }
    }

    __threadfence();                     // device-scope release (cross-XCD)
    cooperative_groups::this_grid().sync();

    // ======== Phase B: attention + output projection ========
    const int b    = blockIdx.x >> 5;
    const int jblk = (blockIdx.x & 31) * 32;

    __shared__ unsigned short hls[32][132];   // [l_local][d], 8.25 KB

#pragma unroll
    for (int hh = 0; hh < 2; ++hh) {
        const int h  = wv + hh * 4;
        const int bh = b * NH + h;

        s4 bk0 = *(const s4*)(Kt + ((size_t)bh * L_ + jblk + m) * DK + q * 4);
        s4 bk1 = *(const s4*)(Kt + ((size_t)bh * L_ + jblk + 16 + m) * DK + q * 4);

        f4 O0 = {0.f, 0.f, 0.f, 0.f}, O1 = {0.f, 0.f, 0.f, 0.f};
        float ls0 = 0.f, ls1 = 0.f;
        const unsigned short* qbase = Qt + (size_t)bh * L_ * DK + q * 4;
        const unsigned short* vbase = Vt + ((size_t)bh * DK + m) * L_ + q * 4;

#pragma unroll 4
        for (int i0 = 0; i0 < L_; i0 += 16) {
            s4 aq = *(const s4*)(qbase + (size_t)(i0 + m) * DK);
            s4 av = *(const s4*)(vbase + i0);

            f4 z = {0.f, 0.f, 0.f, 0.f};
            f4 S0 = MFMA16(aq, bk0, z);     // S[i0+q*4+r][jblk+m]
            f4 S1 = MFMA16(aq, bk1, z);     // S[i0+q*4+r][jblk+16+m]

            float p00 = __expf(S0[0]), p01 = __expf(S0[1]);
            float p02 = __expf(S0[2]), p03 = __expf(S0[3]);
            float p10 = __expf(S1[0]), p11 = __expf(S1[1]);
            float p12 = __expf(S1[2]), p13 = __expf(S1[3]);
            ls0 += (p00 + p01) + (p02 + p03);
            ls1 += (p10 + p11) + (p12 + p13);

            s4 pb0, pb1;
            pb0[0] = (short)f2bf(p00); pb0[1] = (short)f2bf(p01);
            pb0[2] = (short)f2bf(p02); pb0[3] = (short)f2bf(p03);
            pb1[0] = (short)f2bf(p10); pb1[1] = (short)f2bf(p11);
            pb1[2] = (short)f2bf(p12); pb1[3] = (short)f2bf(p13);

            O0 = MFMA16(av, pb0, O0);       // O[v=q*4+r][col] += V*P
            O1 = MFMA16(av, pb1, O1);
        }

        ls0 += __shfl_xor(ls0, 16, 64);
        ls0 += __shfl_xor(ls0, 32, 64);
        ls1 += __shfl_xor(ls1, 16, 64);
        ls1 += __shfl_xor(ls1, 32, 64);
        const float inv0 = 1.f / ls0, inv1 = 1.f / ls1;

        uint2 o0, o1;
        o0.x = pack2(O0[0] * inv0, O0[1] * inv0);
        o0.y = pack2(O0[2] * inv0, O0[3] * inv0);
        o1.x = pack2(O1[0] * inv1, O1[1] * inv1);
        o1.y = pack2(O1[2] * inv1, O1[3] * inv1);
        *(uint2*)&hls[m][h * 16 + q * 4]      = o0;
        *(uint2*)&hls[16 + m][h * 16 + q * 4] = o1;
    }

    __syncthreads();

#pragma unroll
    for (int t = 0; t < 2; ++t) {
        const int oc = wv * 2 + t;
        const int o0 = oc * 16;
        const float* Wrow = Wo + ((size_t)b * D_ + o0 + m) * D_;

        f4 acc0 = {0.f, 0.f, 0.f, 0.f}, acc1 = {0.f, 0.f, 0.f, 0.f};
#pragma unroll
        for (int kb = 0; kb < 8; ++kb) {
            const int k4 = kb * 16 + q * 4;
            float4 wf = *(const float4*)(Wrow + k4);
            s4 a  = pack4(wf.x, wf.y, wf.z, wf.w);
            s4 b0 = *(const s4*)&hls[m][k4];        // B[k][n=l] = hls[l][k]
            s4 b1 = *(const s4*)&hls[16 + m][k4];
            acc0 = MFMA16(a, b0, acc0);
            acc1 = MFMA16(a, b1, acc1);
        }

        float* op = out + ((size_t)b * D_ + o0 + q * 4) * L_ + jblk + m;
        op[0]      = acc0[0]; op[L_]     = acc0[1];
        op[2 * L_] = acc0[2]; op[3 * L_] = acc0[3];
        op += 16;
        op[0]      = acc1[0]; op[L_]     = acc1[1];
        op[2 * L_] = acc1[2]; op[3 * L_] = acc1[3];
    }
}

// ---------------------------------------------------------------------------
extern "C" void kernel_launch(void* const* d_in, const int* in_sizes, int n_in,
                              void* d_out, int out_size, void* d_ws, size_t ws_size,
                              hipStream_t stream) {
    const float* x  = (const float*)d_in[0];
    const float* Wq = (const float*)d_in[1];
    const float* Wk = (const float*)d_in[2];
    const float* Wv = (const float*)d_in[3];
    const float* Wo = (const float*)d_in[4];
    float* out = (float*)d_out;

    const size_t SEG = (size_t)B_ * NH * DK * L_;   // 1,048,576 elements
    unsigned short* Qt = (unsigned short*)d_ws;     // bf16 [bh][l][k], 2 MB
    unsigned short* Kt = Qt + SEG;                  // bf16 [bh][j][k], 2 MB
    unsigned short* Vt = Kt + SEG;                  // bf16 [bh][v][i], 2 MB

    void* args[] = {(void*)&x, (void*)&Wq, (void*)&Wk, (void*)&Wv, (void*)&Wo,
                    (void*)&Qt, (void*)&Kt, (void*)&Vt, (void*)&out};
    hipLaunchCooperativeKernel((const void*)fused_kernel,
                               dim3(256), dim3(256), args, 0, stream);
}

// Round 10
// 103.931 us; speedup vs baseline: 1.7223x; 1.7223x over previous
//
#include <hip/hip_runtime.h>
#include <hip/hip_bf16.h>

#define B_ 8
#define D_ 128
#define NH 8
#define L_ 1024
#define DK 16

typedef __attribute__((ext_vector_type(4))) short s4;
typedef __attribute__((ext_vector_type(4))) float f4;

static __device__ __forceinline__ unsigned short f2bf(float f) {
    __hip_bfloat16 h = __float2bfloat16(f);
    return *reinterpret_cast<unsigned short*>(&h);
}
static __device__ __forceinline__ unsigned pack2(float a, float b) {
    return (unsigned)f2bf(a) | ((unsigned)f2bf(b) << 16);
}
static __device__ __forceinline__ s4 pack4(float a, float b, float c, float d) {
    union { unsigned u[2]; s4 v; } un;
    un.u[0] = pack2(a, b);
    un.u[1] = pack2(c, d);
    return un.v;
}

// 16x16x16 bf16 MFMA: D = A*B + C.  A[m=lane&15][k=(lane>>4)*4+jj],
// B[k=(lane>>4)*4+jj][n=lane&15], C/D[row=(lane>>4)*4+reg][col=lane&15].
// (A/B/C mapping HW-verified in rounds 4-7 end-to-end.)
// NOTE R9 lesson: the 512-thread attn_out restructure caused post-timing
// divergence under graph replay; this 256-thread shape passed the full
// harness (R7).  Do not re-widen the block without re-verifying post-timing.
#if __has_builtin(__builtin_amdgcn_mfma_f32_16x16x16_bf16)
#define MFMA16(a, b, c) __builtin_amdgcn_mfma_f32_16x16x16_bf16(a, b, c, 0, 0, 0)
#elif __has_builtin(__builtin_amdgcn_mfma_f32_16x16x16bf16_1k)
#define MFMA16(a, b, c) __builtin_amdgcn_mfma_f32_16x16x16bf16_1k(a, b, c, 0, 0, 0)
#else
static __device__ __forceinline__ f4 mfma16_asm(s4 a, s4 b, f4 c) {
    f4 d;
    asm volatile("v_mfma_f32_16x16x16_bf16 %0, %1, %2, %3"
                 : "=&v"(d) : "v"(a), "v"(b), "v"(c));
    return d;
}
#define MFMA16(a, b, c) mfma16_asm(a, b, c)
#endif

// ---------------------------------------------------------------------------
// Kernel 1: MFMA QKV projection, x read transposed directly from global
// (fp32 dword loads; bf16 pack on the fly).  One wave per (bh, which,
// 32-wide l-tile).  K = 128 -> 8 steps, 2 MFMA/step.  Epilogue:
//   Qt[bh][l][k]  (packed b64)       which==0
//   Kt[bh][j][k]  *0.25, packed b64  which==1
//   Vt[bh][v][i]  (short stores)     which==2
// grid (8, 64, 3), block 256.
// ---------------------------------------------------------------------------
__global__ __launch_bounds__(256)
void proj_kernel(const float* __restrict__ x,
                 const float* __restrict__ Wq,
                 const float* __restrict__ Wk,
                 const float* __restrict__ Wv,
                 unsigned short* __restrict__ Qt,
                 unsigned short* __restrict__ Kt,
                 unsigned short* __restrict__ Vt) {
    const int lane = threadIdx.x & 63;
    const int wv   = threadIdx.x >> 6;
    const int m = lane & 15, q = lane >> 4;
    const int bh = blockIdx.y, b = bh >> 3, h = bh & 7;
    const int which = blockIdx.z;
    const int n0 = (blockIdx.x * 4 + wv) * 32;

    const float* W = (which == 0) ? Wq : (which == 1) ? Wk : Wv;
    const float* Wrow = W + ((size_t)((h * B_ + b) * DK + m)) * D_;  // A row m
    const float* xb = x + (size_t)b * D_ * L_ + n0 + m;

    f4 acc0 = {0.f, 0.f, 0.f, 0.f}, acc1 = {0.f, 0.f, 0.f, 0.f};
#pragma unroll
    for (int kb = 0; kb < 8; ++kb) {
        const int k4 = kb * 16 + q * 4;
        float4 wf = *(const float4*)(Wrow + k4);
        s4 a = pack4(wf.x, wf.y, wf.z, wf.w);

        const float* xc = xb + (size_t)k4 * L_;
        float b00 = xc[0];           float b01 = xc[L_];
        float b02 = xc[2 * L_];      float b03 = xc[3 * L_];
        float b10 = xc[16];          float b11 = xc[L_ + 16];
        float b12 = xc[2 * L_ + 16]; float b13 = xc[3 * L_ + 16];
        s4 bf0 = pack4(b00, b01, b02, b03);
        s4 bf1 = pack4(b10, b11, b12, b13);

        acc0 = MFMA16(a, bf0, acc0);
        acc1 = MFMA16(a, bf1, acc1);
    }

    if (which == 2) {
        unsigned short* vp = Vt + ((size_t)bh * DK + q * 4) * L_ + n0 + m;
        vp[0]      = f2bf(acc0[0]); vp[L_]     = f2bf(acc0[1]);
        vp[2 * L_] = f2bf(acc0[2]); vp[3 * L_] = f2bf(acc0[3]);
        vp += 16;
        vp[0]      = f2bf(acc1[0]); vp[L_]     = f2bf(acc1[1]);
        vp[2 * L_] = f2bf(acc1[2]); vp[3 * L_] = f2bf(acc1[3]);
    } else {
        const float sc = (which == 1) ? 0.25f : 1.0f;
        unsigned short* T = (which == 0) ? Qt : Kt;
        uint2 u0, u1;
        u0.x = pack2(acc0[0] * sc, acc0[1] * sc);
        u0.y = pack2(acc0[2] * sc, acc0[3] * sc);
        u1.x = pack2(acc1[0] * sc, acc1[1] * sc);
        u1.y = pack2(acc1[2] * sc, acc1[3] * sc);
        *(uint2*)(T + ((size_t)bh * L_ + n0 + m) * DK + q * 4)      = u0;
        *(uint2*)(T + ((size_t)bh * L_ + n0 + 16 + m) * DK + q * 4) = u1;
    }
}

// ---------------------------------------------------------------------------
// Kernel 2: FUSED attention + output projection.  One block per (b, 32 cols).
// Phase 1: each wave handles 2 heads (wv, wv+4) x 2 j-tiles, sharing aq/av
//   loads across tiles; normalized head tile -> LDS hls[l_local][d] (bf16,
//   rows padded to 132 shorts).
// Phase 2: out[b][o][jblk..+31] = Wo[b] @ hls (B-operand straight from LDS).
// grid (32, 8), block 256.   (R7-verified shape)
// ---------------------------------------------------------------------------
__global__ __launch_bounds__(256)
void attn_out_kernel(const unsigned short* __restrict__ Qt,
                     const unsigned short* __restrict__ Kt,
                     const unsigned short* __restrict__ Vt,
                     const float* __restrict__ Wo,
                     float* __restrict__ out) {
    const int lane = threadIdx.x & 63;
    const int wv   = threadIdx.x >> 6;
    const int m = lane & 15, q = lane >> 4;
    const int b    = blockIdx.y;
    const int jblk = blockIdx.x * 32;

    __shared__ unsigned short hls[32][132];   // [l_local][d], 8.25 KB

    // ---- Phase 1: attention for heads wv and wv+4, columns jblk..jblk+31
#pragma unroll
    for (int hh = 0; hh < 2; ++hh) {
        const int h  = wv + hh * 4;
        const int bh = b * NH + h;

        s4 bk0 = *(const s4*)(Kt + ((size_t)bh * L_ + jblk + m) * DK + q * 4);
        s4 bk1 = *(const s4*)(Kt + ((size_t)bh * L_ + jblk + 16 + m) * DK + q * 4);

        f4 O0 = {0.f, 0.f, 0.f, 0.f}, O1 = {0.f, 0.f, 0.f, 0.f};
        float ls0 = 0.f, ls1 = 0.f;
        const unsigned short* qbase = Qt + (size_t)bh * L_ * DK + q * 4;
        const unsigned short* vbase = Vt + ((size_t)bh * DK + m) * L_ + q * 4;

#pragma unroll 4
        for (int i0 = 0; i0 < L_; i0 += 16) {
            s4 aq = *(const s4*)(qbase + (size_t)(i0 + m) * DK);
            s4 av = *(const s4*)(vbase + i0);

            f4 z = {0.f, 0.f, 0.f, 0.f};
            f4 S0 = MFMA16(aq, bk0, z);     // S[i0+q*4+r][jblk+m]
            f4 S1 = MFMA16(aq, bk1, z);     // S[i0+q*4+r][jblk+16+m]

            float p00 = __expf(S0[0]), p01 = __expf(S0[1]);
            float p02 = __expf(S0[2]), p03 = __expf(S0[3]);
            float p10 = __expf(S1[0]), p11 = __expf(S1[1]);
            float p12 = __expf(S1[2]), p13 = __expf(S1[3]);
            ls0 += (p00 + p01) + (p02 + p03);
            ls1 += (p10 + p11) + (p12 + p13);

            s4 pb0, pb1;
            pb0[0] = (short)f2bf(p00); pb0[1] = (short)f2bf(p01);
            pb0[2] = (short)f2bf(p02); pb0[3] = (short)f2bf(p03);
            pb1[0] = (short)f2bf(p10); pb1[1] = (short)f2bf(p11);
            pb1[2] = (short)f2bf(p12); pb1[3] = (short)f2bf(p13);

            O0 = MFMA16(av, pb0, O0);       // O[v=q*4+r][col] += V*P
            O1 = MFMA16(av, pb1, O1);
        }

        ls0 += __shfl_xor(ls0, 16, 64);
        ls0 += __shfl_xor(ls0, 32, 64);
        ls1 += __shfl_xor(ls1, 16, 64);
        ls1 += __shfl_xor(ls1, 32, 64);
        const float inv0 = 1.f / ls0, inv1 = 1.f / ls1;

        // head tile rows l_local = {m, 16+m}, cols d = h*16 + q*4 + r
        uint2 o0, o1;
        o0.x = pack2(O0[0] * inv0, O0[1] * inv0);
        o0.y = pack2(O0[2] * inv0, O0[3] * inv0);
        o1.x = pack2(O1[0] * inv1, O1[1] * inv1);
        o1.y = pack2(O1[2] * inv1, O1[3] * inv1);
        *(uint2*)&hls[m][h * 16 + q * 4]      = o0;
        *(uint2*)&hls[16 + m][h * 16 + q * 4] = o1;
    }

    __syncthreads();

    // ---- Phase 2: out[b][o0+q*4+r][jblk(+16)+m], 2 o-chunks per wave
#pragma unroll
    for (int t = 0; t < 2; ++t) {
        const int oc = wv * 2 + t;
        const int o0 = oc * 16;
        const float* Wrow = Wo + ((size_t)b * D_ + o0 + m) * D_;

        f4 acc0 = {0.f, 0.f, 0.f, 0.f}, acc1 = {0.f, 0.f, 0.f, 0.f};
#pragma unroll
        for (int kb = 0; kb < 8; ++kb) {
            const int k4 = kb * 16 + q * 4;
            float4 wf = *(const float4*)(Wrow + k4);
            s4 a  = pack4(wf.x, wf.y, wf.z, wf.w);
            s4 b0 = *(const s4*)&hls[m][k4];        // B[k][n=l] = hls[l][k]
            s4 b1 = *(const s4*)&hls[16 + m][k4];
            acc0 = MFMA16(a, b0, acc0);
            acc1 = MFMA16(a, b1, acc1);
        }

        float* op = out + ((size_t)b * D_ + o0 + q * 4) * L_ + jblk + m;
        op[0]      = acc0[0]; op[L_]     = acc0[1];
        op[2 * L_] = acc0[2]; op[3 * L_] = acc0[3];
        op += 16;
        op[0]      = acc1[0]; op[L_]     = acc1[1];
        op[2 * L_] = acc1[2]; op[3 * L_] = acc1[3];
    }
}

// ---------------------------------------------------------------------------
extern "C" void kernel_launch(void* const* d_in, const int* in_sizes, int n_in,
                              void* d_out, int out_size, void* d_ws, size_t ws_size,
                              hipStream_t stream) {
    const float* x  = (const float*)d_in[0];
    const float* Wq = (const float*)d_in[1];
    const float* Wk = (const float*)d_in[2];
    const float* Wv = (const float*)d_in[3];
    const float* Wo = (const float*)d_in[4];
    float* out = (float*)d_out;

    const size_t SEG = (size_t)B_ * NH * DK * L_;   // 1,048,576 elements
    unsigned short* Qt = (unsigned short*)d_ws;     // bf16 [bh][l][k], 2 MB
    unsigned short* Kt = Qt + SEG;                  // bf16 [bh][j][k], 2 MB
    unsigned short* Vt = Kt + SEG;                  // bf16 [bh][v][i], 2 MB

    proj_kernel<<<dim3(8, B_ * NH, 3), 256, 0, stream>>>(x, Wq, Wk, Wv, Qt, Kt, Vt);
    attn_out_kernel<<<dim3(32, B_), 256, 0, stream>>>(Qt, Kt, Vt, Wo, out);
}